// Round 3
// baseline (503.552 us; speedup 1.0000x reference)
//
#include <hip/hip_runtime.h>
#include <math.h>

#define NCLASS 32000
#define NROWS  2048
#define NSEG   4              // segments per row
#define SEGF4  2000           // float4s per segment (8000/4)
#define T1     256            // threads per block, kernel 1
#define KPT    8              // float4-pairs per thread (256*8=2048 >= 2000, tail predicated)

#define TAU_D 10.373491181781864
#define E_D   2.718281828459045

// Principal-branch Lambert W, mirrors the reference's 8 Halley iterations.
__device__ __forceinline__ double lambertw_d(double y) {
    double ey1 = fmax(E_D * y + 1.0, 0.0);
    double w_small = -1.0 + sqrt(2.0 * ey1);
    double ys = fmax(y, 1.0 + 1e-6);
    double ly = log(ys);
    double w_big = ly - log(fmax(ly, 1e-6));
    double w = (y < 1.0) ? w_small : w_big;
#pragma unroll
    for (int i = 0; i < 8; ++i) {
        double ew = exp(w);
        double f = w * ew - y;
        double wp1 = w + 1.0;
        double safe_wp1 = (fabs(wp1) > 1e-6) ? wp1 : 1e-6;
        double denom = ew * wp1 - (w + 2.0) * f / (2.0 * safe_wp1);
        if (!(fabs(denom) > 1e-12)) denom = 1e-12;
        w = w - f / denom;
    }
    return w;
}

// Per-element update: 2 transcendentals (exp(x) reconstructed as exp(x/4)^4).
__device__ __forceinline__ void upd(float x, float t,
                                    float& s1, float& sT, float& st,
                                    float& A, float& Bv) {
    float ex4 = __expf(x * 0.25f);
    float ex2 = ex4 * ex4;
    s1 += ex2 * ex2;        // e^x
    sT += ex4;              // e^{x/4}
    float et = __expf(t * 0.25f);
    st += et;               // e^{t/4}
    A  = fmaf(et, t, A);    // e^{t/4} * t
    Bv = fmaf(et, x, Bv);   // e^{t/4} * x
}

// Kernel 1: one block per (row, segment). All 16 dwordx4 loads issued
// back-to-back before any use -> 8 KB in flight per wave.
__global__ __launch_bounds__(T1) void sums_kernel(
    const float* __restrict__ logits,
    const float* __restrict__ teacher,
    float* __restrict__ ws)          // [NROWS][NSEG][5]
{
    const int row = blockIdx.x >> 2;
    const int seg = blockIdx.x & 3;
    const size_t base = (size_t)row * NCLASS;
    const float4* __restrict__ lg = (const float4*)(logits  + base) + seg * SEGF4;
    const float4* __restrict__ tc = (const float4*)(teacher + base) + seg * SEGF4;
    const int tid = threadIdx.x;

    float4 xv[KPT], tv[KPT];
    // Issue every load before any use; clamp the (rare) OOB tail lanes.
#pragma unroll
    for (int k = 0; k < KPT; ++k) {
        int j = tid + k * T1;
        int jc = j < SEGF4 ? j : (SEGF4 - 1);
        xv[k] = lg[jc];
        tv[k] = tc[jc];
    }

    float s1 = 0.f, sT = 0.f, st = 0.f, A = 0.f, Bv = 0.f;
#pragma unroll
    for (int k = 0; k < KPT; ++k) {
        if (tid + k * T1 < SEGF4) {
            upd(xv[k].x, tv[k].x, s1, sT, st, A, Bv);
            upd(xv[k].y, tv[k].y, s1, sT, st, A, Bv);
            upd(xv[k].z, tv[k].z, s1, sT, st, A, Bv);
            upd(xv[k].w, tv[k].w, s1, sT, st, A, Bv);
        }
    }

    // wave-64 shuffle reduction
#pragma unroll
    for (int off = 32; off > 0; off >>= 1) {
        s1 += __shfl_down(s1, off);
        sT += __shfl_down(sT, off);
        st += __shfl_down(st, off);
        A  += __shfl_down(A,  off);
        Bv += __shfl_down(Bv, off);
    }

    __shared__ float red[T1 / 64][5];
    const int wave = tid >> 6;
    const int lane = tid & 63;
    if (lane == 0) {
        red[wave][0] = s1; red[wave][1] = sT; red[wave][2] = st;
        red[wave][3] = A;  red[wave][4] = Bv;
    }
    __syncthreads();

    if (tid < 5) {
        float acc = 0.f;
#pragma unroll
        for (int w = 0; w < T1 / 64; ++w) acc += red[w][tid];
        ws[(size_t)blockIdx.x * 5 + tid] = acc;   // [row*4+seg][5]
    }
}

// Kernel 2: per-row scalar math (fp64) + global reduction. 8 blocks x 256,
// one row per thread; sums the 4 segment partials first.
__global__ __launch_bounds__(256) void finalize_kernel(
    const float* __restrict__ logits,
    const int*   __restrict__ targets,
    const float* __restrict__ ones,
    const float* __restrict__ ws,
    float* __restrict__ out)
{
    const int r = blockIdx.x * 256 + threadIdx.x;   // 8*256 == NROWS exactly

    float fs1 = 0.f, fsT = 0.f, fst = 0.f, fA = 0.f, fB = 0.f;
#pragma unroll
    for (int s = 0; s < NSEG; ++s) {
        const float* p = ws + ((size_t)r * NSEG + s) * 5;
        fs1 += p[0]; fsT += p[1]; fst += p[2]; fA += p[3]; fB += p[4];
    }

    const float xt = logits[(size_t)r * NCLASS + (size_t)targets[r]];
    const float o0 = ones[2 * r + 0];
    const float o1 = ones[2 * r + 1];

    const double lse   = log((double)fs1);
    const double lseT  = log((double)fsT);
    const double lseTt = log((double)fst);

    const double ce = lse - (double)xt;
    const double kl = ((double)fA - (double)fB) / ((double)fst * 4.0)
                      - lseTt + lseT;

    const double base = (double)o0 * ce + 16.0 * (double)o1 * kl;

    const double y = 0.5 * fmax(-2.0 / E_D, (base - TAU_D));   // LAM = 1
    const double w = lambertw_d(y);
    const double sigma = exp(-w);
    double loss = (base - TAU_D) * sigma + w * w;               // log(sigma)^2 = w^2

    // block reduction (4 waves of 64)
#pragma unroll
    for (int off = 32; off > 0; off >>= 1)
        loss += __shfl_down(loss, off);

    __shared__ double red2[4];
    const int wave = threadIdx.x >> 6;
    const int lane = threadIdx.x & 63;
    if (lane == 0) red2[wave] = loss;
    __syncthreads();

    if (threadIdx.x == 0) {
        double acc = red2[0] + red2[1] + red2[2] + red2[3];
        atomicAdd(out, (float)(acc / 2048.0));
    }
}

extern "C" void kernel_launch(void* const* d_in, const int* in_sizes, int n_in,
                              void* d_out, int out_size, void* d_ws, size_t ws_size,
                              hipStream_t stream) {
    const float* logits  = (const float*)d_in[0];
    const float* teacher = (const float*)d_in[1];
    const int*   targets = (const int*)d_in[2];
    const float* ones    = (const float*)d_in[3];
    float* out = (float*)d_out;
    float* ws  = (float*)d_ws;

    hipMemsetAsync(out, 0, sizeof(float) * (size_t)out_size, stream);

    sums_kernel<<<NROWS * NSEG, T1, 0, stream>>>(logits, teacher, ws);
    finalize_kernel<<<NROWS / 256, 256, 0, stream>>>(logits, targets, ones, ws, out);
}